// Round 13
// baseline (701.179 us; speedup 1.0000x reference)
//
#include <hip/hip_runtime.h>
#include <hip/hip_bf16.h>
#include <math.h>

namespace {

constexpr int Bq = 8, Tq = 4096, Dq = 256, Lq = 2, Hq = 4;
constexpr int DKq = 128, DVq = 256, HKq = 32, HVq = 64;
constexpr int Nq = Tq / 64;
constexpr int Mq = Bq * Tq;
constexpr int SQ = 896;                       // fused qkvg+gk row stride
constexpr float SCALEq = 0.17677669529663688f;
constexpr int WL = 1114112;                   // per-layer Wt elems

typedef __hip_bfloat16 bf16;
typedef __attribute__((ext_vector_type(8))) short bf16x8;
typedef __attribute__((ext_vector_type(4))) float f32x4;

__device__ __forceinline__ float b2f(bf16 x) { return __bfloat162float(x); }

__device__ __forceinline__ bf16x8 ld8(const bf16* p) { return *(const bf16x8*)p; }
__device__ __forceinline__ bf16x8 ld8(const float* p) {
  const float4* q4 = (const float4*)p;
  float4 a = q4[0], b = q4[1];
  float v[8] = {a.x, a.y, a.z, a.w, b.x, b.y, b.z, b.w};
  bf16x8 r;
#pragma unroll
  for (int i = 0; i < 8; i++) r[i] = __builtin_bit_cast(short, __float2bfloat16(v[i]));
  return r;
}

// XOR-swizzle of K-index within 64-elem chunks (A-tile LDS, conflict-free ds_read_b128)
__device__ __forceinline__ int swzk(int k, int row) {
  return (k & ~63) | ((((k >> 3) & 7) ^ (row & 7)) << 3) | (k & 7);
}

// fragment-major index for W: frag block (ct,k0,kk,nt) = 64 lanes x 8 elems, 1KB contig
__device__ __forceinline__ size_t fidx(int n, int k, int K) {
  int ct = n >> 7, nt = (n >> 4) & 7, lr = n & 15;
  int k0 = k >> 6, kk = (k >> 5) & 1, lg = (k >> 3) & 3, e = k & 7;
  int fi = ((ct * (K >> 6) + k0) * 2 + kk) * 8 + nt;
  return (size_t)fi * 512 + (lg * 16 + lr) * 8 + e;
}

// ---------------- weight prep (stores FRAG-MAJOR hi/lo) ----------------
__device__ __forceinline__ void wsplit2(float v, bf16* hi, bf16* lo) {
  bf16 h = __float2bfloat16(v);
  *hi = h; *lo = __float2bfloat16(v - b2f(h));
}

// layout per layer (elems): fused[896][256] hi@0 lo@229376; wo hi@458752 lo@524288;
// m1 hi@589824 lo@720896; m2 hi@851968 lo@983040. head @ 2228224 (hi), +32768 (lo).
__global__ void k_wprep(const float* __restrict__ wq, const float* __restrict__ wk,
                        const float* __restrict__ wv, const float* __restrict__ wg,
                        const float* __restrict__ g1, const float* __restrict__ g2,
                        const float* __restrict__ wo, const float* __restrict__ m1,
                        const float* __restrict__ m2, const float* __restrict__ hw,
                        bf16* __restrict__ Wt) {
  int g = blockIdx.x * 256 + threadIdx.x;
  if (g >= 2 * 540672 + 32768) return;
  if (g < 2 * 540672) {
    int l = g / 540672, r = g % 540672;
    bf16* dst = Wt + (size_t)l * WL;
    if (r < 196608) {
      int k, nf; float v;
      if (r < 32768)       { int r2 = r;          k = r2 >> 7; nf = (r2 & 127);       v = wq[l*32768 + r2]; }
      else if (r < 65536)  { int r2 = r - 32768;  k = r2 >> 7; nf = 128 + (r2 & 127); v = wk[l*32768 + r2]; }
      else if (r < 131072) { int r2 = r - 65536;  k = r2 >> 8; nf = 256 + (r2 & 255); v = wv[l*65536 + r2]; }
      else                 { int r2 = r - 131072; k = r2 >> 8; nf = 512 + (r2 & 255); v = wg[l*65536 + r2]; }
      size_t fo = fidx(nf, k, 256);
      wsplit2(v, &dst[fo], &dst[229376 + fo]);
    } else if (r < 212992) {            // gk fused: W12 = g1 @ g2
      int r2 = r - 196608; int k = r2 >> 7, n = r2 & 127;
      float v = 0.f;
#pragma unroll
      for (int i = 0; i < 16; i++) v += g1[l*4096 + k*16 + i] * g2[l*2048 + i*128 + n];
      size_t fo = fidx(768 + n, k, 256);
      wsplit2(v, &dst[fo], &dst[229376 + fo]);
    } else if (r < 278528) {
      int r2 = r - 212992; int k = r2 >> 8, n = r2 & 255;
      size_t fo = fidx(n, k, 256);
      wsplit2(wo[l*65536 + r2], &dst[458752 + fo], &dst[524288 + fo]);
    } else if (r < 409600) {
      int r2 = r - 278528; int k = r2 >> 9, n = r2 & 511;
      size_t fo = fidx(n, k, 256);
      wsplit2(m1[l*131072 + r2], &dst[589824 + fo], &dst[720896 + fo]);
    } else {
      int r2 = r - 409600; int k = r2 >> 8, n = r2 & 255;
      size_t fo = fidx(n, k, 512);
      wsplit2(m2[l*131072 + r2], &dst[851968 + fo], &dst[983040 + fo]);
    }
  } else {
    int r2 = g - 2 * 540672; int k = r2 >> 7, n = r2 & 127;
    size_t fo = fidx(n, k, 256);
    wsplit2(hw[r2], &Wt[2228224 + fo], &Wt[2228224 + 32768 + fo]);
  }
}

// ---------------- embedding ----------------
__global__ void k_embed(const int* __restrict__ tok, const float* __restrict__ emb,
                        float* __restrict__ x) {
  int row = blockIdx.x, i = threadIdx.x;
  x[(size_t)row * Dq + i] = emb[(size_t)tok[row] * Dq + i];
}

// ---------------- layernorm ----------------
__global__ void k_ln(const float* __restrict__ x, const float* __restrict__ w,
                     const float* __restrict__ bb, bf16* __restrict__ h) {
  int row = blockIdx.x, i = threadIdx.x;
  float v = x[(size_t)row * Dq + i];
  float s = v, s2 = v * v;
#pragma unroll
  for (int o = 32; o > 0; o >>= 1) { s += __shfl_down(s, o, 64); s2 += __shfl_down(s2, o, 64); }
  __shared__ float rs[4], rs2[4];
  if ((i & 63) == 0) { rs[i >> 6] = s; rs2[i >> 6] = s2; }
  __syncthreads();
  float sum = rs[0] + rs[1] + rs[2] + rs[3];
  float sum2 = rs2[0] + rs2[1] + rs2[2] + rs2[3];
  float mu = sum * (1.f / Dq);
  float var = fmaxf(sum2 * (1.f / Dq) - mu * mu, 0.f);
  float r = rsqrtf(var + 1e-5f);
  h[(size_t)row * Dq + i] = __float2bfloat16((v - mu) * r * w[i] + bb[i]);
}

// ------- MFMA GEMM: full-K A panel in 64KB swizzled LDS (ONE barrier per 256-K chunk);
// ------- B hi/lo streamed as coalesced frags from L2. Optional fused RMSNorm+swish gate on A.
// W frag-major hi/lo. EPI: 0=none, 2=gelu, 3=log_sigmoid/16 on cols>=768.
template <typename AT, typename OT, int EPI, bool BIAS, bool ACC, bool GATEA>
__global__ __launch_bounds__(256, 2) void k_mgemm8(const AT* __restrict__ A, int lda,
                                                   const bf16* __restrict__ Whf,
                                                   const bf16* __restrict__ Wlf,
                                                   const float* __restrict__ bias,
                                                   OT* __restrict__ C, int ldc, int K,
                                                   const bf16* __restrict__ GQ,
                                                   const float* __restrict__ gnw) {
  __shared__ __attribute__((aligned(16))) bf16 At[128 * 256];  // 64KB, swizzled
  int tid = threadIdx.x;
  int lane = tid & 63, wave = tid >> 6;
  int lr = lane & 15, lg = lane >> 4;
  int wm = (wave >> 1) * 64, wn = (wave & 1) * 64;
  int row0 = blockIdx.x * 128;
  int ct = blockIdx.y, nk = K >> 6;
  f32x4 acc[4][4];
#pragma unroll
  for (int m = 0; m < 4; m++)
#pragma unroll
    for (int n = 0; n < 4; n++) acc[m][n] = (f32x4){0.f, 0.f, 0.f, 0.f};

  for (int kc = 0; kc < K; kc += 256) {
    if (kc) __syncthreads();
    // stage full 128x256 A chunk, swizzled (optionally gated)
#pragma unroll
    for (int p = 0; p < 16; p++) {
      int cix = p * 256 + tid, r = cix >> 5, j = (cix & 31) * 8;
      bf16x8 v = ld8(A + (size_t)(row0 + r) * lda + kc + j);
      if constexpr (GATEA) {
        float o[8]; float s = 0.f;
#pragma unroll
        for (int i = 0; i < 8; i++) { o[i] = b2f(__builtin_bit_cast(bf16, (short)v[i])); s += o[i] * o[i]; }
        s += __shfl_xor(s, 1, 64); s += __shfl_xor(s, 2, 64); s += __shfl_xor(s, 4, 64);
        float rr = rsqrtf(s * (1.f / 64.f) + 1e-5f);
        bf16x8 g8 = *(const bf16x8*)(GQ + (size_t)(row0 + r) * SQ + 512 + j);
#pragma unroll
        for (int i = 0; i < 8; i++) {
          float g = b2f(__builtin_bit_cast(bf16, (short)g8[i]));
          float sw = g / (1.f + expf(-g));
          v[i] = __builtin_bit_cast(short, __float2bfloat16(o[i] * rr * gnw[(j + i) & 63] * sw));
        }
      }
      *(bf16x8*)&At[r * 256 + swzk(j, r)] = v;
    }
    __syncthreads();
    // barrier-free compute over the whole 256-K chunk
#pragma unroll
    for (int k0l = 0; k0l < 256; k0l += 64) {
      int k0 = kc + k0l;
      int k0i = k0 >> 6;
#pragma unroll
      for (int kk = 0; kk < 64; kk += 32) {
        int fb = ((ct * nk + k0i) * 2 + (kk >> 5)) * 8 + (wn >> 4);
        const bf16* bhp = Whf + (size_t)fb * 512 + lane * 8;
        const bf16* blp = Wlf + (size_t)fb * 512 + lane * 8;
        bf16x8 af[4], bh4[4], bl4[4];
#pragma unroll
        for (int n = 0; n < 4; n++) {                // coalesced 1KB frag loads from L2
          bh4[n] = *(const bf16x8*)(bhp + n * 512);
          bl4[n] = *(const bf16x8*)(blp + n * 512);
        }
#pragma unroll
        for (int m = 0; m < 4; m++) {
          int ar = wm + m * 16 + lr;
          af[m] = *(bf16x8*)&At[ar * 256 + swzk(k0l + kk + lg * 8, ar)];
        }
#pragma unroll
        for (int m = 0; m < 4; m++)
#pragma unroll
          for (int n = 0; n < 4; n++) {
            acc[m][n] = __builtin_amdgcn_mfma_f32_16x16x32_bf16(af[m], bh4[n], acc[m][n], 0, 0, 0);
            acc[m][n] = __builtin_amdgcn_mfma_f32_16x16x32_bf16(af[m], bl4[n], acc[m][n], 0, 0, 0);
          }
      }
    }
  }
#pragma unroll
  for (int m = 0; m < 4; m++) {
#pragma unroll
    for (int n = 0; n < 4; n++) {
      int col = ct * 128 + wn + n * 16 + lr;
      int rowb = row0 + wm + m * 16 + lg * 4;
      float bv = BIAS ? bias[col] : 0.f;
#pragma unroll
      for (int j = 0; j < 4; j++) {
        float v = acc[m][n][j] + bv;
        if (EPI == 2) v = 0.5f * v * (1.f + erff(v * 0.70710678118654752f));
        if (EPI == 3 && col >= 768) {
          float t = v + bias[col - 768];
          v = (fminf(t, 0.f) - log1pf(expf(-fabsf(t)))) * (1.f / 16.f);
        }
        size_t oi = (size_t)(rowb + j) * ldc + col;
        if constexpr (ACC) C[oi] += v;
        else if constexpr (sizeof(OT) == 2) C[oi] = __float2bfloat16(v);
        else C[oi] = v;
      }
    }
  }
}

// ---------------- intra-chunk: MFMA qk/pv/kv, hi/lo operands ----------------
__global__ __launch_bounds__(256) void k_intra(bf16* QKVG,
                                               bf16* __restrict__ O,
                                               bf16* __restrict__ KVt,
                                               float* __restrict__ GL) {
  int blk = blockIdx.x;
  int n = blk & 63, h = (blk >> 6) & 3, b = blk >> 8;
  __shared__ __attribute__((aligned(16))) char smem[47488];
  float* bshT = (float*)smem;              // [32][66] cum gates (dead after staging)
  bf16*  kvS  = (bf16*)smem;               // [32][72] alias over bshT (late)
  float* glv  = (float*)(smem + 8448);     // [32]
  bf16*  vT   = (bf16*)(smem + 8576);      // [64][72] v^T[e][c]
  bf16*  kiAH = (bf16*)(smem + 17792);     // [32][72] ki^T[d][c] hi
  bf16*  kiAL = (bf16*)(smem + 22400);     //          lo
  bf16*  qsH  = (bf16*)(smem + 27008);     // [64][40] qs[c][d] hi
  bf16*  qsL  = (bf16*)(smem + 32128);     //          lo
  bf16*  kiBH = (bf16*)(smem + 37248);     // [64][40] ki[m][d] hi
  bf16*  kiBL = (bf16*)(smem + 42368);     //          lo
  bf16*  aH   = (bf16*)(smem + 27008);     // [64][72] att hi (alias, post-QK)
  bf16*  aL   = (bf16*)(smem + 36224);     // [64][72] att lo
  int tid = threadIdx.x;
  int lane = tid & 63, wave = tid >> 6;
  int lr = lane & 15, lg = lane >> 4;
  size_t tbase = (size_t)b * Tq + n * 64;
  int bh = b * Hq + h;

  // gates -> bshT (transposed)
  {
    int c = tid >> 2, dc = (tid & 3) * 8;
    bf16x8 g8 = *(const bf16x8*)(QKVG + (tbase + c) * SQ + 768 + h * HKq + dc);
#pragma unroll
    for (int i = 0; i < 8; i++) bshT[(dc + i) * 66 + c] = b2f(__builtin_bit_cast(bf16, (short)g8[i]));
  }
  __syncthreads();
  // Kogge-Stone inclusive cumsum along c (lane = c)
#pragma unroll
  for (int dd = 0; dd < 8; dd++) {
    int d = wave * 8 + dd;
    float v = bshT[d * 66 + lane];
#pragma unroll
    for (int o = 1; o < 64; o <<= 1) {
      float t = __shfl_up(v, (unsigned)o, 64);
      if (lane >= o) v += t;
    }
    bshT[d * 66 + lane] = v;
  }
  __syncthreads();
  if (tid < 32) {
    float g = expf(bshT[tid * 66 + 63]);
    glv[tid] = g;
    GL[(size_t)(bh * Nq + n) * 32 + tid] = g;
  }
  // stage q (hi/lo + export), ki (hi/lo, two layouts), v^T
  {
    int c = tid >> 2, dc = (tid & 3) * 8;
    size_t qoff = (tbase + c) * SQ + h * HKq + dc;
    bf16x8 q8 = *(const bf16x8*)(QKVG + qoff);
    bf16x8 k8 = *(const bf16x8*)(QKVG + qoff + 128);
    bf16x8 qh8, ql8, kh8, kl8;
#pragma unroll
    for (int i = 0; i < 8; i++) {
      float bv = bshT[(dc + i) * 66 + c];
      float qv = b2f(__builtin_bit_cast(bf16, (short)q8[i])) * expf(bv) * SCALEq;
      float kv = b2f(__builtin_bit_cast(bf16, (short)k8[i])) * expf(-bv);
      bf16 qh = __float2bfloat16(qv); bf16 ql = __float2bfloat16(qv - b2f(qh));
      bf16 kh = __float2bfloat16(kv); bf16 kl = __float2bfloat16(kv - b2f(kh));
      qh8[i] = __builtin_bit_cast(short, qh); ql8[i] = __builtin_bit_cast(short, ql);
      kh8[i] = __builtin_bit_cast(short, kh); kl8[i] = __builtin_bit_cast(short, kl);
      kiAH[(dc + i) * 72 + c] = kh; kiAL[(dc + i) * 72 + c] = kl;
    }
    *(bf16x8*)&qsH[c * 40 + dc] = qh8;
    *(bf16x8*)&qsL[c * 40 + dc] = ql8;
    *(bf16x8*)&kiBH[c * 40 + dc] = kh8;
    *(bf16x8*)&kiBL[c * 40 + dc] = kl8;
    *(bf16x8*)(QKVG + qoff) = qh8;     // export scaled q for k_inter
  }
#pragma unroll
  for (int p = 0; p < 2; p++) {
    int idx = p * 256 + tid;
    int c = idx & 63, ec = (idx >> 6) * 8;
    bf16x8 v8 = *(const bf16x8*)(QKVG + (tbase + c) * SQ + 256 + h * HVq + ec);
#pragma unroll
    for (int i = 0; i < 8; i++) vT[(ec + i) * 72 + c] = __builtin_bit_cast(bf16, (short)v8[i]);
  }
  __syncthreads();
  // QK^T with hi/lo cross terms
  f32x4 accq[4];
#pragma unroll
  for (int t = 0; t < 4; t++) accq[t] = (f32x4){0.f, 0.f, 0.f, 0.f};
  {
    bf16x8 afh = *(bf16x8*)&qsH[(wave * 16 + lr) * 40 + lg * 8];
    bf16x8 afl = *(bf16x8*)&qsL[(wave * 16 + lr) * 40 + lg * 8];
#pragma unroll
    for (int t = 0; t < 4; t++) {
      bf16x8 bh = *(bf16x8*)&kiBH[(t * 16 + lr) * 40 + lg * 8];
      bf16x8 bl = *(bf16x8*)&kiBL[(t * 16 + lr) * 40 + lg * 8];
      accq[t] = __builtin_amdgcn_mfma_f32_16x16x32_bf16(afh, bh, accq[t], 0, 0, 0);
      accq[t] = __builtin_amdgcn_mfma_f32_16x16x32_bf16(afh, bl, accq[t], 0, 0, 0);
      accq[t] = __builtin_amdgcn_mfma_f32_16x16x32_bf16(afl, bh, accq[t], 0, 0, 0);
    }
  }
  __syncthreads();               // qs/kiB dead; aH/aL alias them
  // mask + hi/lo split -> aH/aL
#pragma unroll
  for (int t = 0; t < 4; t++)
#pragma unroll
    for (int j = 0; j < 4; j++) {
      int row = wave * 16 + lg * 4 + j;
      int col = t * 16 + lr;
      float v = (col <= row) ? accq[t][j] : 0.f;
      bf16 hi = __float2bfloat16(v);
      aH[row * 72 + col] = hi;
      aL[row * 72 + col] = __float2bfloat16(v - b2f(hi));
    }
  __syncthreads();
  // PV: o[c][e] = att @ v
  f32x4 acco[4];
#pragma unroll
  for (int t = 0; t < 4; t++) acco[t] = (f32x4){0.f, 0.f, 0.f, 0.f};
#pragma unroll
  for (int ks = 0; ks < 2; ks++) {
    bf16x8 ah = *(bf16x8*)&aH[(wave * 16 + lr) * 72 + ks * 32 + lg * 8];
    bf16x8 al = *(bf16x8*)&aL[(wave * 16 + lr) * 72 + ks * 32 + lg * 8];
#pragma unroll
    for (int t = 0; t < 4; t++) {
      bf16x8 bfv = *(bf16x8*)&vT[(t * 16 + lr) * 72 + ks * 32 + lg * 8];
      acco[t] = __builtin_amdgcn_mfma_f32_16x16x32_bf16(ah, bfv, acco[t], 0, 0, 0);
      acco[t] = __builtin_amdgcn_mfma_f32_16x16x32_bf16(al, bfv, acco[t], 0, 0, 0);
    }
  }
#pragma unroll
  for (int t = 0; t < 4; t++)
#pragma unroll
    for (int j = 0; j < 4; j++) {
      int row = wave * 16 + lg * 4 + j, e = t * 16 + lr;
      O[(tbase + row) * DVq + h * HVq + e] = __float2bfloat16(acco[t][j]);
    }
  // kv[d][e] = (ki^T @ v) * g_last[d], ki hi/lo
  f32x4 acck[2];
  acck[0] = (f32x4){0.f, 0.f, 0.f, 0.f};
  acck[1] = (f32x4){0.f, 0.f, 0.f, 0.f};
#pragma unroll
  for (int ks = 0; ks < 2; ks++) {
    bf16x8 akh = *(bf16x8*)&kiAH[((wave >> 1) * 16 + lr) * 72 + ks * 32 + lg * 8];
    bf16x8 akl = *(bf16x8*)&kiAL[((wave >> 1) * 16 + lr) * 72 + ks * 32 + lg * 8];
#pragma unroll
    for (int t = 0; t < 2; t++) {
      bf16x8 bfv = *(bf16x8*)&vT[(((wave & 1) * 2 + t) * 16 + lr) * 72 + ks * 32 + lg * 8];
      acck[t] = __builtin_amdgcn_mfma_f32_16x16x32_bf16(akh, bfv, acck[t], 0, 0, 0);
      acck[t] = __builtin_amdgcn_mfma_f32_16x16x32_bf16(akl, bfv, acck[t], 0, 0, 0);
    }
  }
#pragma unroll
  for (int t = 0; t < 2; t++)
#pragma unroll
    for (int j = 0; j < 4; j++) {
      int d = (wave >> 1) * 16 + lg * 4 + j;
      int e = ((wave & 1) * 2 + t) * 16 + lr;
      kvS[d * 72 + e] = __float2bfloat16(acck[t][j] * glv[d]);
    }
  __syncthreads();
  size_t kbase = (size_t)(bh * Nq + n) * 2048;
  {
    int d = tid >> 3, cc = (tid & 7) * 8;
    *(bf16x8*)&KVt[kbase + d * 64 + cc] = *(bf16x8*)&kvS[d * 72 + cc];
  }
}

// ---------------- inter-chunk scan + o_inter ----------------
__global__ __launch_bounds__(256) void k_inter(const bf16* __restrict__ QKVG,
                                               const float* __restrict__ GL,
                                               const bf16* __restrict__ KVt,
                                               bf16* __restrict__ O) {
  int blk = blockIdx.x;
  int es = blk & 7, h = (blk >> 3) & 3, b = blk >> 5;
  int e0 = es * 8;
  __shared__ __attribute__((aligned(16))) bf16 kvl[64 * 32 * 8]; // [n][d][8e]
  __shared__ float gl[64 * 32];
  __shared__ float S[64 * 32 * 8];                               // [n][d][8e]
  int tid = threadIdx.x;
  int bh = b * Hq + h;
  const float* glp = GL + (size_t)bh * Nq * 32;
#pragma unroll
  for (int p = 0; p < 8; p++) { int i = p * 256 + tid; gl[i] = glp[i]; }
  const bf16* kvp = KVt + (size_t)bh * Nq * 2048 + e0;
#pragma unroll
  for (int p = 0; p < 8; p++) {
    int c8 = p * 256 + tid;
    *(bf16x8*)&kvl[c8 * 8] = *(const bf16x8*)(kvp + (size_t)(c8 >> 5) * 2048 + (size_t)(c8 & 31) * 64);
  }
  __syncthreads();
  {
    int pe = tid & 7, pd = tid >> 3;
    float s = 0.f;
    for (int n = 0; n < 64; n++) {
      S[(n * 32 + pd) * 8 + pe] = s;
      s = s * gl[n * 32 + pd] + b2f(kvl[(n * 32 + pd) * 8 + pe]);
    }
  }
  __syncthreads();
  int c = tid >> 2, ep = tid & 3;
  for (int n = 0; n < 64; n++) {
    size_t tbase = (size_t)b * Tq + n * 64;
    const bf16* qp = QKVG + (tbase + c) * SQ + h * HKq;
    const float* Sp = &S[n * 256];
    float a0 = 0.f, a1 = 0.f;
#pragma unroll
    for (int j = 0; j < 4; j++) {
      bf16x8 q8 = *(const bf16x8*)(qp + j * 8);
#pragma unroll
      for (int i = 0; i < 8; i++) {
        float qf = b2f(__builtin_bit_cast(bf16, (short)q8[i]));
        int d = j * 8 + i;
        a0 += qf * Sp[d * 8 + ep];
        a1 += qf * Sp[d * 8 + ep + 4];
      }
    }
    size_t oi = (tbase + c) * DVq + h * HVq + e0 + ep;
    O[oi] = __float2bfloat16(b2f(O[oi]) + a0);
    O[oi + 4] = __float2bfloat16(b2f(O[oi + 4]) + a1);
  }
}

} // namespace

extern "C" void kernel_launch(void* const* d_in, const int* in_sizes, int n_in,
                              void* d_out, int out_size, void* d_ws, size_t ws_size,
                              hipStream_t stream) {
  const int*   tok  = (const int*)d_in[0];
  const float* emb  = (const float*)d_in[1];
  const float* ln_w = (const float*)d_in[2];
  const float* ln_b = (const float*)d_in[3];
  const float* wq   = (const float*)d_in[4];
  const float* wk   = (const float*)d_in[5];
  const float* wv   = (const float*)d_in[6];
  const float* wg   = (const float*)d_in[7];
  const float* gkw1 = (const float*)d_in[8];
  const float* gkw2 = (const float*)d_in[9];
  const float* gkb2 = (const float*)d_in[10];
  const float* gnw  = (const float*)d_in[11];
  const float* wo   = (const float*)d_in[12];
  const float* mw1  = (const float*)d_in[13];
  const float* mb1  = (const float*)d_in[14];
  const float* mw2  = (const float*)d_in[15];
  const float* mb2  = (const float*)d_in[16];
  const float* hw   = (const float*)d_in[17];
  const float* hb   = (const float*)d_in[18];

  if (ws_size < 134217728u) return;
  char* w = (char*)d_ws;
  float* X    = (float*)w;                        // [M,256] f32    33.5MB
  bf16*  Ob   = (bf16*)(w + 33554432);            // [M,256] bf16   16.8MB
  bf16*  Hbf  = Ob;                               // overlay (disjoint lifetime)
  bf16*  QKVG = (bf16*)(w + 50331648);            // [M,896] bf16   58.7MB
  bf16*  KVt  = (bf16*)(w + 109051904);           // [BH,64,32,64]   8.4MB
  float* GLb  = (float*)(w + 117440512);          // [BH,64,32]      0.26MB
  bf16*  Wt   = (bf16*)(w + 117702656);           // split weights   4.6MB
  bf16*  MLPH = QKVG;                             // [M,512] overlay

  dim3 blk(256);
  k_wprep<<<4353, blk, 0, stream>>>(wq, wk, wv, wg, gkw1, gkw2, wo, mw1, mw2, hw, Wt);
  k_embed<<<Mq, blk, 0, stream>>>(tok, emb, X);

  for (int l = 0; l < Lq; l++) {
    const bf16* Wl = Wt + (size_t)l * WL;
    k_ln<<<Mq, blk, 0, stream>>>(X, ln_w + l * Dq, ln_b + l * Dq, Hbf);
    k_mgemm8<bf16, bf16, 3, false, false, false><<<dim3(256, 7), blk, 0, stream>>>(Hbf, 256, Wl, Wl + 229376, gkb2 + l * DKq, QKVG, SQ, 256, nullptr, nullptr);
    k_intra<<<Bq * Hq * Nq, blk, 0, stream>>>(QKVG, Ob, KVt, GLb);
    k_inter<<<Bq * Hq * 8, blk, 0, stream>>>(QKVG, GLb, KVt, Ob);
    k_mgemm8<bf16, float, 0, false, true, true><<<dim3(256, 2), blk, 0, stream>>>(Ob, 256, Wl + 458752, Wl + 524288, nullptr, X, 256, 256, QKVG, gnw + l * HVq);
    k_ln<<<Mq, blk, 0, stream>>>(X, ln_w + l * Dq, ln_b + l * Dq, Hbf);
    k_mgemm8<bf16, bf16, 2, true, false, false><<<dim3(256, 4), blk, 0, stream>>>(Hbf, 256, Wl + 589824, Wl + 720896, mb1 + l * 2 * Dq, MLPH, 512, 256, nullptr, nullptr);
    k_mgemm8<bf16, float, 0, true, true, false><<<dim3(256, 2), blk, 0, stream>>>(MLPH, 512, Wl + 851968, Wl + 983040, mb2 + l * Dq, X, 256, 512, nullptr, nullptr);
  }
  k_mgemm8<float, float, 0, true, false, false><<<dim3(256, 1), blk, 0, stream>>>(X, 256, Wt + 2228224, Wt + 2228224 + 32768, hb, (float*)d_out, 128, 256, nullptr, nullptr);
}

// Round 14
// 643.810 us; speedup vs baseline: 1.0891x; 1.0891x over previous
//
#include <hip/hip_runtime.h>
#include <hip/hip_bf16.h>
#include <math.h>

namespace {

constexpr int Bq = 8, Tq = 4096, Dq = 256, Lq = 2, Hq = 4;
constexpr int DKq = 128, DVq = 256, HKq = 32, HVq = 64;
constexpr int Nq = Tq / 64;
constexpr int Mq = Bq * Tq;
constexpr int SQ = 896;                       // fused qkvg+gk row stride
constexpr float SCALEq = 0.17677669529663688f;
constexpr int WL = 1114112;                   // per-layer Wt elems

typedef __hip_bfloat16 bf16;
typedef __attribute__((ext_vector_type(8))) short bf16x8;
typedef __attribute__((ext_vector_type(4))) float f32x4;

__device__ __forceinline__ float b2f(bf16 x) { return __bfloat162float(x); }

__device__ __forceinline__ bf16x8 ld8(const bf16* p) { return *(const bf16x8*)p; }
__device__ __forceinline__ bf16x8 ld8(const float* p) {
  const float4* q4 = (const float4*)p;
  float4 a = q4[0], b = q4[1];
  float v[8] = {a.x, a.y, a.z, a.w, b.x, b.y, b.z, b.w};
  bf16x8 r;
#pragma unroll
  for (int i = 0; i < 8; i++) r[i] = __builtin_bit_cast(short, __float2bfloat16(v[i]));
  return r;
}

// XOR-swizzle of K-index within 64-elem chunks (A-tile LDS, conflict-free ds_read_b128)
__device__ __forceinline__ int swzk(int k, int row) {
  return (k & ~63) | ((((k >> 3) & 7) ^ (row & 7)) << 3) | (k & 7);
}

// fragment-major index for W: frag block (ct,k0,kk,nt) = 64 lanes x 8 elems, 1KB contig
__device__ __forceinline__ size_t fidx(int n, int k, int K) {
  int ct = n >> 7, nt = (n >> 4) & 7, lr = n & 15;
  int k0 = k >> 6, kk = (k >> 5) & 1, lg = (k >> 3) & 3, e = k & 7;
  int fi = ((ct * (K >> 6) + k0) * 2 + kk) * 8 + nt;
  return (size_t)fi * 512 + (lg * 16 + lr) * 8 + e;
}

// ---------------- weight prep (stores FRAG-MAJOR hi/lo) ----------------
__device__ __forceinline__ void wsplit2(float v, bf16* hi, bf16* lo) {
  bf16 h = __float2bfloat16(v);
  *hi = h; *lo = __float2bfloat16(v - b2f(h));
}

// layout per layer (elems): fused[896][256] hi@0 lo@229376; wo hi@458752 lo@524288;
// m1 hi@589824 lo@720896; m2 hi@851968 lo@983040. head @ 2228224 (hi), +32768 (lo).
__global__ void k_wprep(const float* __restrict__ wq, const float* __restrict__ wk,
                        const float* __restrict__ wv, const float* __restrict__ wg,
                        const float* __restrict__ g1, const float* __restrict__ g2,
                        const float* __restrict__ wo, const float* __restrict__ m1,
                        const float* __restrict__ m2, const float* __restrict__ hw,
                        bf16* __restrict__ Wt) {
  int g = blockIdx.x * 256 + threadIdx.x;
  if (g >= 2 * 540672 + 32768) return;
  if (g < 2 * 540672) {
    int l = g / 540672, r = g % 540672;
    bf16* dst = Wt + (size_t)l * WL;
    if (r < 196608) {
      int k, nf; float v;
      if (r < 32768)       { int r2 = r;          k = r2 >> 7; nf = (r2 & 127);       v = wq[l*32768 + r2]; }
      else if (r < 65536)  { int r2 = r - 32768;  k = r2 >> 7; nf = 128 + (r2 & 127); v = wk[l*32768 + r2]; }
      else if (r < 131072) { int r2 = r - 65536;  k = r2 >> 8; nf = 256 + (r2 & 255); v = wv[l*65536 + r2]; }
      else                 { int r2 = r - 131072; k = r2 >> 8; nf = 512 + (r2 & 255); v = wg[l*65536 + r2]; }
      size_t fo = fidx(nf, k, 256);
      wsplit2(v, &dst[fo], &dst[229376 + fo]);
    } else if (r < 212992) {            // gk fused: W12 = g1 @ g2
      int r2 = r - 196608; int k = r2 >> 7, n = r2 & 127;
      float v = 0.f;
#pragma unroll
      for (int i = 0; i < 16; i++) v += g1[l*4096 + k*16 + i] * g2[l*2048 + i*128 + n];
      size_t fo = fidx(768 + n, k, 256);
      wsplit2(v, &dst[fo], &dst[229376 + fo]);
    } else if (r < 278528) {
      int r2 = r - 212992; int k = r2 >> 8, n = r2 & 255;
      size_t fo = fidx(n, k, 256);
      wsplit2(wo[l*65536 + r2], &dst[458752 + fo], &dst[524288 + fo]);
    } else if (r < 409600) {
      int r2 = r - 278528; int k = r2 >> 9, n = r2 & 511;
      size_t fo = fidx(n, k, 256);
      wsplit2(m1[l*131072 + r2], &dst[589824 + fo], &dst[720896 + fo]);
    } else {
      int r2 = r - 409600; int k = r2 >> 8, n = r2 & 255;
      size_t fo = fidx(n, k, 512);
      wsplit2(m2[l*131072 + r2], &dst[851968 + fo], &dst[983040 + fo]);
    }
  } else {
    int r2 = g - 2 * 540672; int k = r2 >> 7, n = r2 & 127;
    size_t fo = fidx(n, k, 256);
    wsplit2(hw[r2], &Wt[2228224 + fo], &Wt[2228224 + 32768 + fo]);
  }
}

// ---------------- embedding: 8 rows/block, vectorized ----------------
__global__ void k_embed(const int* __restrict__ tok, const float* __restrict__ emb,
                        float* __restrict__ x) {
  int row = blockIdx.x * 8 + (threadIdx.x >> 5);
  int j = (threadIdx.x & 31) * 8;
  const float4* s = (const float4*)(emb + (size_t)tok[row] * Dq + j);
  float4* d = (float4*)(x + (size_t)row * Dq + j);
  d[0] = s[0]; d[1] = s[1];
}

// ---------------- layernorm: 8 rows/block, 32-lane groups, vectorized ----------------
__global__ void k_ln(const float* __restrict__ x, const float* __restrict__ w,
                     const float* __restrict__ bb, bf16* __restrict__ h) {
  int row = blockIdx.x * 8 + (threadIdx.x >> 5);
  int j = (threadIdx.x & 31) * 8;
  const float4* xp = (const float4*)(x + (size_t)row * Dq + j);
  float4 a = xp[0], b4 = xp[1];
  float v[8] = {a.x, a.y, a.z, a.w, b4.x, b4.y, b4.z, b4.w};
  float s = 0.f, s2 = 0.f;
#pragma unroll
  for (int i = 0; i < 8; i++) { s += v[i]; s2 += v[i] * v[i]; }
#pragma unroll
  for (int o = 16; o > 0; o >>= 1) { s += __shfl_xor(s, o, 64); s2 += __shfl_xor(s2, o, 64); }
  float mu = s * (1.f / Dq);
  float var = fmaxf(s2 * (1.f / Dq) - mu * mu, 0.f);
  float r = rsqrtf(var + 1e-5f);
  bf16x8 o8;
#pragma unroll
  for (int i = 0; i < 8; i++)
    o8[i] = __builtin_bit_cast(short, __float2bfloat16((v[i] - mu) * r * w[j + i] + bb[j + i]));
  *(bf16x8*)(h + (size_t)row * Dq + j) = o8;
}

// ------- MFMA GEMM: A in 16KB swizzled LDS; B hi/lo streamed as COALESCED frags (L2) ----
// W frag-major hi/lo. EPI: 0=none, 2=gelu, 3=log_sigmoid/16 on cols>=768.
// GATEA: apply fused RMSNorm+swish gate to A rows during staging (wo GEMM).
template <typename AT, typename OT, int EPI, bool BIAS, bool ACC, bool GATEA>
__global__ __launch_bounds__(256, 4) void k_mgemm7(const AT* __restrict__ A, int lda,
                                                   const bf16* __restrict__ Whf,
                                                   const bf16* __restrict__ Wlf,
                                                   const float* __restrict__ bias,
                                                   OT* __restrict__ C, int ldc, int K,
                                                   const bf16* __restrict__ GQ,
                                                   const float* __restrict__ gnw) {
  __shared__ __attribute__((aligned(16))) bf16 At[128 * 64];   // 16KB, swizzled
  int tid = threadIdx.x;
  int lane = tid & 63, wave = tid >> 6;
  int lr = lane & 15, lg = lane >> 4;
  int wm = (wave >> 1) * 64, wn = (wave & 1) * 64;
  int row0 = blockIdx.x * 128;
  int ct = blockIdx.y, nk = K >> 6;
  f32x4 acc[4][4];
#pragma unroll
  for (int m = 0; m < 4; m++)
#pragma unroll
    for (int n = 0; n < 4; n++) acc[m][n] = (f32x4){0.f, 0.f, 0.f, 0.f};

  for (int k0 = 0; k0 < K; k0 += 64) {
    int k0i = k0 >> 6;
#pragma unroll
    for (int p = 0; p < 4; p++) {
      int cix = p * 256 + tid, r = cix >> 3, j = (cix & 7) * 8;
      bf16x8 v = ld8(A + (size_t)(row0 + r) * lda + k0 + j);
      if constexpr (GATEA) {
        // head == the 64-wide k0 chunk; 8 staging lanes cover it
        float o[8]; float s = 0.f;
#pragma unroll
        for (int i = 0; i < 8; i++) { o[i] = b2f(__builtin_bit_cast(bf16, (short)v[i])); s += o[i] * o[i]; }
        s += __shfl_xor(s, 1, 64); s += __shfl_xor(s, 2, 64); s += __shfl_xor(s, 4, 64);
        float rr = rsqrtf(s * (1.f / 64.f) + 1e-5f);
        bf16x8 g8 = *(const bf16x8*)(GQ + (size_t)(row0 + r) * SQ + 512 + k0 + j);
#pragma unroll
        for (int i = 0; i < 8; i++) {
          float g = b2f(__builtin_bit_cast(bf16, (short)g8[i]));
          float sw = g / (1.f + expf(-g));
          v[i] = __builtin_bit_cast(short, __float2bfloat16(o[i] * rr * gnw[(k0 + j + i) & 63] * sw));
        }
      }
      *(bf16x8*)&At[r * 64 + swzk(j, r)] = v;       // swizzle on store
    }
    __syncthreads();
#pragma unroll
    for (int kk = 0; kk < 64; kk += 32) {
      int fb = ((ct * nk + k0i) * 2 + (kk >> 5)) * 8 + (wn >> 4);
      const bf16* bhp = Whf + (size_t)fb * 512 + lane * 8;
      const bf16* blp = Wlf + (size_t)fb * 512 + lane * 8;
      bf16x8 af[4], bh4[4], bl4[4];
#pragma unroll
      for (int n = 0; n < 4; n++) {                  // coalesced 1KB frag loads from L2
        bh4[n] = *(const bf16x8*)(bhp + n * 512);
        bl4[n] = *(const bf16x8*)(blp + n * 512);
      }
#pragma unroll
      for (int m = 0; m < 4; m++) {
        int ar = wm + m * 16 + lr;
        af[m] = *(bf16x8*)&At[ar * 64 + swzk(kk + lg * 8, ar)];
      }
#pragma unroll
      for (int m = 0; m < 4; m++)
#pragma unroll
        for (int n = 0; n < 4; n++) {
          acc[m][n] = __builtin_amdgcn_mfma_f32_16x16x32_bf16(af[m], bh4[n], acc[m][n], 0, 0, 0);
          acc[m][n] = __builtin_amdgcn_mfma_f32_16x16x32_bf16(af[m], bl4[n], acc[m][n], 0, 0, 0);
        }
    }
    __syncthreads();
  }
#pragma unroll
  for (int m = 0; m < 4; m++) {
#pragma unroll
    for (int n = 0; n < 4; n++) {
      int col = ct * 128 + wn + n * 16 + lr;
      int rowb = row0 + wm + m * 16 + lg * 4;
      float bv = BIAS ? bias[col] : 0.f;
#pragma unroll
      for (int j = 0; j < 4; j++) {
        float v = acc[m][n][j] + bv;
        if (EPI == 2) v = 0.5f * v * (1.f + erff(v * 0.70710678118654752f));
        if (EPI == 3 && col >= 768) {
          float t = v + bias[col - 768];
          v = (fminf(t, 0.f) - log1pf(expf(-fabsf(t)))) * (1.f / 16.f);
        }
        size_t oi = (size_t)(rowb + j) * ldc + col;
        if constexpr (ACC) C[oi] += v;
        else if constexpr (sizeof(OT) == 2) C[oi] = __float2bfloat16(v);
        else C[oi] = v;
      }
    }
  }
}

// ---------------- intra-chunk: MFMA qk/pv/kv, hi/lo operands ----------------
__global__ __launch_bounds__(256) void k_intra(bf16* QKVG,
                                               bf16* __restrict__ O,
                                               bf16* __restrict__ KVt,
                                               float* __restrict__ GL) {
  int blk = blockIdx.x;
  int n = blk & 63, h = (blk >> 6) & 3, b = blk >> 8;
  __shared__ __attribute__((aligned(16))) char smem[47488];
  float* bshT = (float*)smem;              // [32][66] cum gates (dead after staging)
  bf16*  kvS  = (bf16*)smem;               // [32][72] alias over bshT (late)
  float* glv  = (float*)(smem + 8448);     // [32]
  bf16*  vT   = (bf16*)(smem + 8576);      // [64][72] v^T[e][c]
  bf16*  kiAH = (bf16*)(smem + 17792);     // [32][72] ki^T[d][c] hi
  bf16*  kiAL = (bf16*)(smem + 22400);     //          lo
  bf16*  qsH  = (bf16*)(smem + 27008);     // [64][40] qs[c][d] hi
  bf16*  qsL  = (bf16*)(smem + 32128);     //          lo
  bf16*  kiBH = (bf16*)(smem + 37248);     // [64][40] ki[m][d] hi
  bf16*  kiBL = (bf16*)(smem + 42368);     //          lo
  bf16*  aH   = (bf16*)(smem + 27008);     // [64][72] att hi (alias, post-QK)
  bf16*  aL   = (bf16*)(smem + 36224);     // [64][72] att lo
  int tid = threadIdx.x;
  int lane = tid & 63, wave = tid >> 6;
  int lr = lane & 15, lg = lane >> 4;
  size_t tbase = (size_t)b * Tq + n * 64;
  int bh = b * Hq + h;

  // gates -> bshT (transposed)
  {
    int c = tid >> 2, dc = (tid & 3) * 8;
    bf16x8 g8 = *(const bf16x8*)(QKVG + (tbase + c) * SQ + 768 + h * HKq + dc);
#pragma unroll
    for (int i = 0; i < 8; i++) bshT[(dc + i) * 66 + c] = b2f(__builtin_bit_cast(bf16, (short)g8[i]));
  }
  __syncthreads();
  // Kogge-Stone inclusive cumsum along c (lane = c)
#pragma unroll
  for (int dd = 0; dd < 8; dd++) {
    int d = wave * 8 + dd;
    float v = bshT[d * 66 + lane];
#pragma unroll
    for (int o = 1; o < 64; o <<= 1) {
      float t = __shfl_up(v, (unsigned)o, 64);
      if (lane >= o) v += t;
    }
    bshT[d * 66 + lane] = v;
  }
  __syncthreads();
  if (tid < 32) {
    float g = expf(bshT[tid * 66 + 63]);
    glv[tid] = g;
    GL[(size_t)(bh * Nq + n) * 32 + tid] = g;
  }
  // stage q (hi/lo + export), ki (hi/lo, two layouts), v^T
  {
    int c = tid >> 2, dc = (tid & 3) * 8;
    size_t qoff = (tbase + c) * SQ + h * HKq + dc;
    bf16x8 q8 = *(const bf16x8*)(QKVG + qoff);
    bf16x8 k8 = *(const bf16x8*)(QKVG + qoff + 128);
    bf16x8 qh8, ql8, kh8, kl8;
#pragma unroll
    for (int i = 0; i < 8; i++) {
      float bv = bshT[(dc + i) * 66 + c];
      float qv = b2f(__builtin_bit_cast(bf16, (short)q8[i])) * expf(bv) * SCALEq;
      float kv = b2f(__builtin_bit_cast(bf16, (short)k8[i])) * expf(-bv);
      bf16 qh = __float2bfloat16(qv); bf16 ql = __float2bfloat16(qv - b2f(qh));
      bf16 kh = __float2bfloat16(kv); bf16 kl = __float2bfloat16(kv - b2f(kh));
      qh8[i] = __builtin_bit_cast(short, qh); ql8[i] = __builtin_bit_cast(short, ql);
      kh8[i] = __builtin_bit_cast(short, kh); kl8[i] = __builtin_bit_cast(short, kl);
      kiAH[(dc + i) * 72 + c] = kh; kiAL[(dc + i) * 72 + c] = kl;
    }
    *(bf16x8*)&qsH[c * 40 + dc] = qh8;
    *(bf16x8*)&qsL[c * 40 + dc] = ql8;
    *(bf16x8*)&kiBH[c * 40 + dc] = kh8;
    *(bf16x8*)&kiBL[c * 40 + dc] = kl8;
    *(bf16x8*)(QKVG + qoff) = qh8;     // export scaled q for k_inter
  }
#pragma unroll
  for (int p = 0; p < 2; p++) {
    int idx = p * 256 + tid;
    int c = idx & 63, ec = (idx >> 6) * 8;
    bf16x8 v8 = *(const bf16x8*)(QKVG + (tbase + c) * SQ + 256 + h * HVq + ec);
#pragma unroll
    for (int i = 0; i < 8; i++) vT[(ec + i) * 72 + c] = __builtin_bit_cast(bf16, (short)v8[i]);
  }
  __syncthreads();
  // QK^T with hi/lo cross terms
  f32x4 accq[4];
#pragma unroll
  for (int t = 0; t < 4; t++) accq[t] = (f32x4){0.f, 0.f, 0.f, 0.f};
  {
    bf16x8 afh = *(bf16x8*)&qsH[(wave * 16 + lr) * 40 + lg * 8];
    bf16x8 afl = *(bf16x8*)&qsL[(wave * 16 + lr) * 40 + lg * 8];
#pragma unroll
    for (int t = 0; t < 4; t++) {
      bf16x8 bh = *(bf16x8*)&kiBH[(t * 16 + lr) * 40 + lg * 8];
      bf16x8 bl = *(bf16x8*)&kiBL[(t * 16 + lr) * 40 + lg * 8];
      accq[t] = __builtin_amdgcn_mfma_f32_16x16x32_bf16(afh, bh, accq[t], 0, 0, 0);
      accq[t] = __builtin_amdgcn_mfma_f32_16x16x32_bf16(afh, bl, accq[t], 0, 0, 0);
      accq[t] = __builtin_amdgcn_mfma_f32_16x16x32_bf16(afl, bh, accq[t], 0, 0, 0);
    }
  }
  __syncthreads();               // qs/kiB dead; aH/aL alias them
  // mask + hi/lo split -> aH/aL
#pragma unroll
  for (int t = 0; t < 4; t++)
#pragma unroll
    for (int j = 0; j < 4; j++) {
      int row = wave * 16 + lg * 4 + j;
      int col = t * 16 + lr;
      float v = (col <= row) ? accq[t][j] : 0.f;
      bf16 hi = __float2bfloat16(v);
      aH[row * 72 + col] = hi;
      aL[row * 72 + col] = __float2bfloat16(v - b2f(hi));
    }
  __syncthreads();
  // PV: o[c][e] = att @ v
  f32x4 acco[4];
#pragma unroll
  for (int t = 0; t < 4; t++) acco[t] = (f32x4){0.f, 0.f, 0.f, 0.f};
#pragma unroll
  for (int ks = 0; ks < 2; ks++) {
    bf16x8 ah = *(bf16x8*)&aH[(wave * 16 + lr) * 72 + ks * 32 + lg * 8];
    bf16x8 al = *(bf16x8*)&aL[(wave * 16 + lr) * 72 + ks * 32 + lg * 8];
#pragma unroll
    for (int t = 0; t < 4; t++) {
      bf16x8 bfv = *(bf16x8*)&vT[(t * 16 + lr) * 72 + ks * 32 + lg * 8];
      acco[t] = __builtin_amdgcn_mfma_f32_16x16x32_bf16(ah, bfv, acco[t], 0, 0, 0);
      acco[t] = __builtin_amdgcn_mfma_f32_16x16x32_bf16(al, bfv, acco[t], 0, 0, 0);
    }
  }
#pragma unroll
  for (int t = 0; t < 4; t++)
#pragma unroll
    for (int j = 0; j < 4; j++) {
      int row = wave * 16 + lg * 4 + j, e = t * 16 + lr;
      O[(tbase + row) * DVq + h * HVq + e] = __float2bfloat16(acco[t][j]);
    }
  // kv[d][e] = (ki^T @ v) * g_last[d], ki hi/lo
  f32x4 acck[2];
  acck[0] = (f32x4){0.f, 0.f, 0.f, 0.f};
  acck[1] = (f32x4){0.f, 0.f, 0.f, 0.f};
#pragma unroll
  for (int ks = 0; ks < 2; ks++) {
    bf16x8 akh = *(bf16x8*)&kiAH[((wave >> 1) * 16 + lr) * 72 + ks * 32 + lg * 8];
    bf16x8 akl = *(bf16x8*)&kiAL[((wave >> 1) * 16 + lr) * 72 + ks * 32 + lg * 8];
#pragma unroll
    for (int t = 0; t < 2; t++) {
      bf16x8 bfv = *(bf16x8*)&vT[(((wave & 1) * 2 + t) * 16 + lr) * 72 + ks * 32 + lg * 8];
      acck[t] = __builtin_amdgcn_mfma_f32_16x16x32_bf16(akh, bfv, acck[t], 0, 0, 0);
      acck[t] = __builtin_amdgcn_mfma_f32_16x16x32_bf16(akl, bfv, acck[t], 0, 0, 0);
    }
  }
#pragma unroll
  for (int t = 0; t < 2; t++)
#pragma unroll
    for (int j = 0; j < 4; j++) {
      int d = (wave >> 1) * 16 + lg * 4 + j;
      int e = ((wave & 1) * 2 + t) * 16 + lr;
      kvS[d * 72 + e] = __float2bfloat16(acck[t][j] * glv[d]);
    }
  __syncthreads();
  size_t kbase = (size_t)(bh * Nq + n) * 2048;
  {
    int d = tid >> 3, cc = (tid & 7) * 8;
    *(bf16x8*)&KVt[kbase + d * 64 + cc] = *(bf16x8*)&kvS[d * 72 + cc];
  }
}

// ---------------- inter-chunk scan + o_inter ----------------
__global__ __launch_bounds__(256) void k_inter(const bf16* __restrict__ QKVG,
                                               const float* __restrict__ GL,
                                               const bf16* __restrict__ KVt,
                                               bf16* __restrict__ O) {
  int blk = blockIdx.x;
  int es = blk & 7, h = (blk >> 3) & 3, b = blk >> 5;
  int e0 = es * 8;
  __shared__ __attribute__((aligned(16))) bf16 kvl[64 * 32 * 8]; // [n][d][8e]
  __shared__ float gl[64 * 32];
  __shared__ float S[64 * 32 * 8];                               // [n][d][8e]
  int tid = threadIdx.x;
  int bh = b * Hq + h;
  const float* glp = GL + (size_t)bh * Nq * 32;
#pragma unroll
  for (int p = 0; p < 8; p++) { int i = p * 256 + tid; gl[i] = glp[i]; }
  const bf16* kvp = KVt + (size_t)bh * Nq * 2048 + e0;
#pragma unroll
  for (int p = 0; p < 8; p++) {
    int c8 = p * 256 + tid;
    *(bf16x8*)&kvl[c8 * 8] = *(const bf16x8*)(kvp + (size_t)(c8 >> 5) * 2048 + (size_t)(c8 & 31) * 64);
  }
  __syncthreads();
  {
    int pe = tid & 7, pd = tid >> 3;
    float s = 0.f;
    for (int n = 0; n < 64; n++) {
      S[(n * 32 + pd) * 8 + pe] = s;
      s = s * gl[n * 32 + pd] + b2f(kvl[(n * 32 + pd) * 8 + pe]);
    }
  }
  __syncthreads();
  int c = tid >> 2, ep = tid & 3;
  for (int n = 0; n < 64; n++) {
    size_t tbase = (size_t)b * Tq + n * 64;
    const bf16* qp = QKVG + (tbase + c) * SQ + h * HKq;
    const float* Sp = &S[n * 256];
    float a0 = 0.f, a1 = 0.f;
#pragma unroll
    for (int j = 0; j < 4; j++) {
      bf16x8 q8 = *(const bf16x8*)(qp + j * 8);
#pragma unroll
      for (int i = 0; i < 8; i++) {
        float qf = b2f(__builtin_bit_cast(bf16, (short)q8[i]));
        int d = j * 8 + i;
        a0 += qf * Sp[d * 8 + ep];
        a1 += qf * Sp[d * 8 + ep + 4];
      }
    }
    size_t oi = (tbase + c) * DVq + h * HVq + e0 + ep;
    O[oi] = __float2bfloat16(b2f(O[oi]) + a0);
    O[oi + 4] = __float2bfloat16(b2f(O[oi + 4]) + a1);
  }
}

} // namespace

extern "C" void kernel_launch(void* const* d_in, const int* in_sizes, int n_in,
                              void* d_out, int out_size, void* d_ws, size_t ws_size,
                              hipStream_t stream) {
  const int*   tok  = (const int*)d_in[0];
  const float* emb  = (const float*)d_in[1];
  const float* ln_w = (const float*)d_in[2];
  const float* ln_b = (const float*)d_in[3];
  const float* wq   = (const float*)d_in[4];
  const float* wk   = (const float*)d_in[5];
  const float* wv   = (const float*)d_in[6];
  const float* wg   = (const float*)d_in[7];
  const float* gkw1 = (const float*)d_in[8];
  const float* gkw2 = (const float*)d_in[9];
  const float* gkb2 = (const float*)d_in[10];
  const float* gnw  = (const float*)d_in[11];
  const float* wo   = (const float*)d_in[12];
  const float* mw1  = (const float*)d_in[13];
  const float* mb1  = (const float*)d_in[14];
  const float* mw2  = (const float*)d_in[15];
  const float* mb2  = (const float*)d_in[16];
  const float* hw   = (const float*)d_in[17];
  const float* hb   = (const float*)d_in[18];

  if (ws_size < 134217728u) return;
  char* w = (char*)d_ws;
  float* X    = (float*)w;                        // [M,256] f32    33.5MB
  bf16*  Ob   = (bf16*)(w + 33554432);            // [M,256] bf16   16.8MB
  bf16*  Hbf  = Ob;                               // overlay (disjoint lifetime)
  bf16*  QKVG = (bf16*)(w + 50331648);            // [M,896] bf16   58.7MB
  bf16*  KVt  = (bf16*)(w + 109051904);           // [BH,64,32,64]   8.4MB
  float* GLb  = (float*)(w + 117440512);          // [BH,64,32]      0.26MB
  bf16*  Wt   = (bf16*)(w + 117702656);           // split weights   4.6MB
  bf16*  MLPH = QKVG;                             // [M,512] overlay

  dim3 blk(256);
  k_wprep<<<4353, blk, 0, stream>>>(wq, wk, wv, wg, gkw1, gkw2, wo, mw1, mw2, hw, Wt);
  k_embed<<<Mq / 8, blk, 0, stream>>>(tok, emb, X);

  for (int l = 0; l < Lq; l++) {
    const bf16* Wl = Wt + (size_t)l * WL;
    k_ln<<<Mq / 8, blk, 0, stream>>>(X, ln_w + l * Dq, ln_b + l * Dq, Hbf);
    k_mgemm7<bf16, bf16, 3, false, false, false><<<dim3(256, 7), blk, 0, stream>>>(Hbf, 256, Wl, Wl + 229376, gkb2 + l * DKq, QKVG, SQ, 256, nullptr, nullptr);
    k_intra<<<Bq * Hq * Nq, blk, 0, stream>>>(QKVG, Ob, KVt, GLb);
    k_inter<<<Bq * Hq * 8, blk, 0, stream>>>(QKVG, GLb, KVt, Ob);
    k_mgemm7<bf16, float, 0, false, true, true><<<dim3(256, 2), blk, 0, stream>>>(Ob, 256, Wl + 458752, Wl + 524288, nullptr, X, 256, 256, QKVG, gnw + l * HVq);
    k_ln<<<Mq / 8, blk, 0, stream>>>(X, ln_w + l * Dq, ln_b + l * Dq, Hbf);
    k_mgemm7<bf16, bf16, 2, true, false, false><<<dim3(256, 4), blk, 0, stream>>>(Hbf, 256, Wl + 589824, Wl + 720896, mb1 + l * 2 * Dq, MLPH, 512, 256, nullptr, nullptr);
    k_mgemm7<bf16, float, 0, true, true, false><<<dim3(256, 2), blk, 0, stream>>>(MLPH, 512, Wl + 851968, Wl + 983040, mb2 + l * Dq, X, 256, 512, nullptr, nullptr);
  }
  k_mgemm7<float, float, 0, true, false, false><<<dim3(256, 1), blk, 0, stream>>>(X, 256, Wt + 2228224, Wt + 2228224 + 32768, hb, (float*)d_out, 128, 256, nullptr, nullptr);
}